// Round 5
// baseline (512.240 us; speedup 1.0000x reference)
//
#include <hip/hip_runtime.h>
#include <stdint.h>

// Problem constants
#define B_      4
#define C_      3
#define H_      1024
#define W_      1024
#define OH_     31          // (1024-64)/32 + 1
#define NHS_    64          // 16-row half-strips per image
#define NP_     3844        // B * OH * OH
#define NPOSPB_ 961         // OH*OH
#define EPS_    1e-5f

#define NBLK_    192        // fused grid: 192 blocks x 1024 threads
#define MIDBLK_  16         // blocks that run the MLP middle

// ---------------- ws layout (float offsets) ----------------
#define TILE_PLANE 24576    // 12 bc * 64 hs * 32 tx
#define OFF_TILE  0         // 4 planes * 24576 = 98304
#define OFF_STATS 98304     // 128 floats: s1 sum[32], s1 sq[32], s2 sum[32], s2 sq[32]
#define OFF_BAR   98432     // 4 ints (fallback path only)
#define OFF_A     98436     // 3 * 3844
#define OFF_BV    109968    // 3 * 3844  (end ~486 KB; L2/L3-resident)

typedef float f4 __attribute__((ext_vector_type(4)));

// ---------------- device-global barrier state ----------------
// Zero-initialized at module load; the LAST exiting block resets everything to
// zero, so every launch (and every rocprof replay) sees a clean state. Immune
// to the harness's ws poisoning. idx: 0 = phase-1 done (target 192),
// 1,2 = mid BN barriers (target 16), 3 = A/b done (target 16), 4 = exit (192).
__device__ int g_bar[8];

// All threads fence (push this block's plain stores to the device coherence
// point), syncthreads (waits vmcnt -> all block ops complete), then t0 arrives
// with a device-scope RMW. Consumer side: t0 acquire-spins, syncthreads
// broadcasts. Standard multi-block barrier recipe; same pattern as the proven
// round-3/4 bar16 but with state outside ws.
#define BLK_RELEASE_ARRIVE(idx) do { \
    __threadfence(); __syncthreads(); \
    if (t == 0) __atomic_fetch_add(&g_bar[idx], 1, __ATOMIC_ACQ_REL); \
} while (0)
#define BLK_WAIT(idx, target) do { \
    if (t == 0) { \
        while (__hip_atomic_load(&g_bar[idx], __ATOMIC_ACQUIRE, __HIP_MEMORY_SCOPE_AGENT) < (target)) \
            __builtin_amdgcn_s_sleep(1); \
    } \
    __syncthreads(); \
} while (0)

// ============================================================================
// FUSED: phase1 (all 192 blocks, 4 half-strips each) -> bar(192) ->
// mid (blocks 0..15, round-4-proven 4-wave channel-split body, bar(16) x2) ->
// A/b-done flag -> phase5 (all blocks, 64 rows each).
// Removes 2 kernel boundaries (~15-25 us each in this harness).
// Co-residency: 192 blocks <= 256 CUs at 1 block/CU (LDS 35 KB, VGPR <= 128
// via __launch_bounds__(1024)); launched cooperatively for the formal
// guarantee, round-4 pipeline as fallback.
// ============================================================================
__global__ __launch_bounds__(1024) void fused(
        const float* __restrict__ g,
        const float* __restrict__ s,
        const float* __restrict__ w1f,
        const float* __restrict__ g1f,
        const float* __restrict__ b1f,
        const float* __restrict__ w2f,
        const float* __restrict__ g2f,
        const float* __restrict__ b2f,
        const float* __restrict__ w3f,
        float* __restrict__ ws,
        float* __restrict__ out) {
    __shared__ float zbuf[256 * 33];     // [pos_local][ch] padded stride 33 (mid blocks only)
    __shared__ float red[16][16];
    __shared__ float scs[32], shs[32];
    int t  = threadIdx.x;
    int fb = blockIdx.x;

    // ---------------- phase 1: tile partial sums (4 half-strip units per block) ----------------
    {
        int sub = t >> 8;                 // 0..3 (wave-aligned: 256 = 4 waves)
        int st  = t & 255;
        int blk = fb * 4 + sub;           // original k1 block id 0..767
        int bc = blk >> 6;
        int hs = blk & 63;
        const f4* gp = (const f4*)(g + ((size_t)bc * H_ + (size_t)hs * 16) * W_);
        const f4* sp = (const f4*)(s + ((size_t)bc * H_ + (size_t)hs * 16) * W_);
        float sg = 0.f, ss = 0.f, sgs = 0.f, sgg = 0.f;
#pragma unroll 4
        for (int r = 0; r < 16; r++) {
            f4 gv = gp[r * (W_ / 4) + st];
            f4 sv = __builtin_nontemporal_load(sp + r * (W_ / 4) + st);  // src read exactly once
            sg  += (gv.x + gv.y) + (gv.z + gv.w);
            ss  += (sv.x + sv.y) + (sv.z + sv.w);
            sgs += gv.x * sv.x + gv.y * sv.y + gv.z * sv.z + gv.w * sv.w;
            sgg += gv.x * gv.x + gv.y * gv.y + gv.z * gv.z + gv.w * gv.w;
        }
#pragma unroll
        for (int off = 4; off; off >>= 1) {
            sg  += __shfl_down(sg,  off, 8);
            ss  += __shfl_down(ss,  off, 8);
            sgs += __shfl_down(sgs, off, 8);
            sgg += __shfl_down(sgg, off, 8);
        }
        if ((st & 7) == 0) {
            int tx = st >> 3;
            int base = (bc * NHS_ + hs) * 32 + tx;
            ws[OFF_TILE + 0 * TILE_PLANE + base] = sg;
            ws[OFF_TILE + 1 * TILE_PLANE + base] = ss;
            ws[OFF_TILE + 2 * TILE_PLANE + base] = sgs;
            ws[OFF_TILE + 3 * TILE_PLANE + base] = sgg;
        }
        if (fb == 0 && t < 128) ws[OFF_STATS + t] = 0.f;   // zero stats (ws is poisoned)
    }
    BLK_RELEASE_ARRIVE(0);

    if (fb < MIDBLK_) {
        // ================= mid phases (round-4-proven body) =================
        BLK_WAIT(0, NBLK_);               // all tile partials visible

        int w    = t >> 6;
        int lane = t & 63;
        int k    = w & 3;                                    // channel group 0..3
        int ko8  = __builtin_amdgcn_readfirstlane(k * 8);    // wave-uniform weight base (s_load)
        int pl   = (w >> 2) * 64 + lane;                     // local position 0..255
        int p    = fb * 256 + pl;
        bool ok  = p < NP_;
        int pp   = ok ? p : 0;
        int b    = pp / NPOSPB_;
        int r    = pp % NPOSPB_;
        int oy   = r / OH_, ox = r % OH_;

        // ---- phase A: window sums -> h -> conv1 (my 8 channels) ----
        float h[6], mxv[3], myv[3];
#pragma unroll
        for (int c = 0; c < 3; c++) {
            int bc = b * 3 + c;
            int base = (bc * NHS_ + oy * 2) * 32 + ox;
            float S[4];
#pragma unroll
            for (int plane = 0; plane < 4; plane++) {
                const float* tp = ws + OFF_TILE + plane * TILE_PLANE + base;
                S[plane] = ((tp[0]  + tp[1])  + (tp[32] + tp[33]))
                         + ((tp[64] + tp[65]) + (tp[96] + tp[97]));
            }
            const float inv = 1.f / 4096.f;
            float mx = S[0] * inv, my = S[1] * inv;
            h[c]     = S[2] * inv - mx * my;
            h[3 + c] = S[3] * inv - mx * mx;
            mxv[c] = mx; myv[c] = my;
        }
        float a[8];
#pragma unroll
        for (int j = 0; j < 8; j++) {
            float y = 0.f;
#pragma unroll
            for (int i = 0; i < 6; i++) y += w1f[(ko8 + j) * 6 + i] * h[i];
            a[j] = y;
        }

        // stats1: per-wave shuffle reduce -> LDS -> cross-wave -> atomicAdd
        {
            float sv[8], sq[8];
#pragma unroll
            for (int j = 0; j < 8; j++) { sv[j] = ok ? a[j] : 0.f; sq[j] = sv[j] * sv[j]; }
#pragma unroll
            for (int off = 32; off; off >>= 1) {
#pragma unroll
                for (int j = 0; j < 8; j++) {
                    sv[j] += __shfl_down(sv[j], off, 64);
                    sq[j] += __shfl_down(sq[j], off, 64);
                }
            }
            if (lane == 0) {
#pragma unroll
                for (int j = 0; j < 8; j++) { red[w][j] = sv[j]; red[w][8 + j] = sq[j]; }
            }
        }
        __syncthreads();
        if (t < 64) {
            int o = t & 31; int kk = o >> 3; int col = ((t >= 32) ? 8 : 0) + (o & 7);
            float tot = red[kk][col] + red[kk + 4][col] + red[kk + 8][col] + red[kk + 12][col];
            atomicAdd(&ws[OFF_STATS + ((t >= 32) ? 32 : 0) + o], tot);
        }
        BLK_RELEASE_ARRIVE(1);
        BLK_WAIT(1, MIDBLK_);

        if (t < 32) {
            float sm = __hip_atomic_load(&ws[OFF_STATS + t],      __ATOMIC_RELAXED, __HIP_MEMORY_SCOPE_AGENT);
            float sq = __hip_atomic_load(&ws[OFF_STATS + 32 + t], __ATOMIC_RELAXED, __HIP_MEMORY_SCOPE_AGENT);
            float m = sm * (1.f / NP_);
            float v = sq * (1.f / NP_) - m * m;
            float sc = g1f[t] * rsqrtf(v + EPS_);
            scs[t] = sc; shs[t] = b1f[t] - m * sc;
        }
        __syncthreads();

        // ---- phase B: BN1+ReLU -> z via LDS -> conv2 (my 8 channels) ----
#pragma unroll
        for (int j = 0; j < 8; j++) {
            float zz = fmaxf(a[j] * scs[ko8 + j] + shs[ko8 + j], 0.f);
            zbuf[pl * 33 + ko8 + j] = zz;
        }
        __syncthreads();
        float zal[32];
#pragma unroll
        for (int i = 0; i < 32; i++) zal[i] = zbuf[pl * 33 + i];   // conflict-free
        float y2[8];
#pragma unroll
        for (int j = 0; j < 8; j++) {
            float y = 0.f;
#pragma unroll
            for (int i = 0; i < 32; i++) y += w2f[(ko8 + j) * 32 + i] * zal[i];   // s_load stream
            y2[j] = y;
        }

        // stats2
        {
            float sv[8], sq[8];
#pragma unroll
            for (int j = 0; j < 8; j++) { sv[j] = ok ? y2[j] : 0.f; sq[j] = sv[j] * sv[j]; }
#pragma unroll
            for (int off = 32; off; off >>= 1) {
#pragma unroll
                for (int j = 0; j < 8; j++) {
                    sv[j] += __shfl_down(sv[j], off, 64);
                    sq[j] += __shfl_down(sq[j], off, 64);
                }
            }
            if (lane == 0) {
#pragma unroll
                for (int j = 0; j < 8; j++) { red[w][j] = sv[j]; red[w][8 + j] = sq[j]; }
            }
        }
        __syncthreads();
        if (t < 64) {
            int o = t & 31; int kk = o >> 3; int col = ((t >= 32) ? 8 : 0) + (o & 7);
            float tot = red[kk][col] + red[kk + 4][col] + red[kk + 8][col] + red[kk + 12][col];
            atomicAdd(&ws[OFF_STATS + 64 + ((t >= 32) ? 32 : 0) + o], tot);
        }
        BLK_RELEASE_ARRIVE(2);
        BLK_WAIT(2, MIDBLK_);

        if (t < 32) {
            float sm = __hip_atomic_load(&ws[OFF_STATS + 64 + t], __ATOMIC_RELAXED, __HIP_MEMORY_SCOPE_AGENT);
            float sq = __hip_atomic_load(&ws[OFF_STATS + 96 + t], __ATOMIC_RELAXED, __HIP_MEMORY_SCOPE_AGENT);
            float m = sm * (1.f / NP_);
            float v = sq * (1.f / NP_) - m * m;
            float sc = g2f[t] * rsqrtf(v + EPS_);
            scs[t] = sc; shs[t] = b2f[t] - m * sc;
        }
        __syncthreads();

        // ---- phase C: BN2+ReLU -> z2 via LDS -> conv3 -> A, b ----
#pragma unroll
        for (int j = 0; j < 8; j++) {
            float zz = fmaxf(y2[j] * scs[ko8 + j] + shs[ko8 + j], 0.f);
            zbuf[pl * 33 + ko8 + j] = zz;     // safe: conv2-era reads done before bar(2)
        }
        __syncthreads();
        if (k == 0 && ok) {
            float z2[32];
#pragma unroll
            for (int i = 0; i < 32; i++) z2[i] = zbuf[pl * 33 + i];
#pragma unroll
            for (int c = 0; c < 3; c++) {
                float av = 0.f;
#pragma unroll
                for (int i = 0; i < 32; i++) av += w3f[c * 32 + i] * z2[i];
                ws[OFF_A  + c * NP_ + p] = av;
                ws[OFF_BV + c * NP_ + p] = myv[c] - av * mxv[c];
            }
        }
        BLK_RELEASE_ARRIVE(3);
        BLK_WAIT(3, MIDBLK_);            // other mid blocks' A/b too
    } else {
        BLK_WAIT(3, MIDBLK_);            // non-mid: just wait for A/b
    }

    // ---------------- phase 5: bilinear upsample + out = A*g + b (64 rows/block) ----------------
    {
        int sub = t >> 8;
        int st  = t & 255;
        int row0 = fb * 64 + sub * 16;    // this sub-block's 16 rows; bc uniform (16 | 1024)
        int bc = row0 >> 10;
        int b5 = bc / 3, c5 = bc % 3;
        const float* Abase = ws + OFF_A  + c5 * NP_ + b5 * NPOSPB_;
        const float* Bbase = ws + OFF_BV + c5 * NP_ + b5 * NPOSPB_;
        int x0_[4], x1_[4]; float wx_[4];
#pragma unroll
        for (int j = 0; j < 4; j++) {
            int x = st * 4 + j;
            float fx = (float)x * (30.f / 1023.f);
            int x0 = (int)fx;
            wx_[j] = fx - (float)x0;
            x0_[j] = x0;
            x1_[j] = min(x0 + 1, 30);
        }
        for (int rr = 0; rr < 16; rr++) {
            int y = (row0 & 1023) + rr;
            float fy = (float)y * (30.f / 1023.f);
            int y0 = (int)fy;
            float wy = fy - (float)y0;
            int y1i = min(y0 + 1, 30);
            const float* A0 = Abase + y0  * OH_;
            const float* A1 = Abase + y1i * OH_;
            const float* B0 = Bbase + y0  * OH_;
            const float* B1 = Bbase + y1i * OH_;
            size_t rowoff = ((size_t)bc * H_ + (size_t)y) * W_;
            f4 gv = ((const f4*)(g + rowoff))[st];
            float go[4] = { gv.x, gv.y, gv.z, gv.w };
            float r[4];
#pragma unroll
            for (int j = 0; j < 4; j++) {
                int x0 = x0_[j], x1 = x1_[j];
                float wx = wx_[j];
                float av = (A0[x0] * (1.f - wx) + A0[x1] * wx) * (1.f - wy)
                         + (A1[x0] * (1.f - wx) + A1[x1] * wx) * wy;
                float bb = (B0[x0] * (1.f - wx) + B0[x1] * wx) * (1.f - wy)
                         + (B1[x0] * (1.f - wx) + B1[x1] * wx) * wy;
                r[j] = av * go[j] + bb;
            }
            f4 ov; ov.x = r[0]; ov.y = r[1]; ov.z = r[2]; ov.w = r[3];
            __builtin_nontemporal_store(ov, (f4*)(out + rowoff) + st);   // out never re-read
        }
    }

    // ---------------- exit: last block resets barrier state for next launch ----------------
    __syncthreads();
    if (t == 0) {
        int old = __atomic_fetch_add(&g_bar[4], 1, __ATOMIC_ACQ_REL);
        if (old == NBLK_ - 1) {
            g_bar[0] = 0; g_bar[1] = 0; g_bar[2] = 0; g_bar[3] = 0;
            __threadfence();
            g_bar[4] = 0;
        }
    }
}

// ============================================================================
// Fallback: round-4-proven 3-kernel pipeline (if cooperative launch rejected).
// ============================================================================
__global__ __launch_bounds__(256) void k1_tilesums(
        const float* __restrict__ g,
        const float* __restrict__ s,
        float* __restrict__ ws) {
    int blk = blockIdx.x;
    int bc = blk >> 6;
    int hs = blk & 63;
    int t  = threadIdx.x;
    const f4* gp = (const f4*)(g + ((size_t)bc * H_ + (size_t)hs * 16) * W_);
    const f4* sp = (const f4*)(s + ((size_t)bc * H_ + (size_t)hs * 16) * W_);
    float sg = 0.f, ss = 0.f, sgs = 0.f, sgg = 0.f;
#pragma unroll 4
    for (int r = 0; r < 16; r++) {
        f4 gv = gp[r * (W_ / 4) + t];
        f4 sv = __builtin_nontemporal_load(sp + r * (W_ / 4) + t);
        sg  += (gv.x + gv.y) + (gv.z + gv.w);
        ss  += (sv.x + sv.y) + (sv.z + sv.w);
        sgs += gv.x * sv.x + gv.y * sv.y + gv.z * sv.z + gv.w * sv.w;
        sgg += gv.x * gv.x + gv.y * gv.y + gv.z * gv.z + gv.w * gv.w;
    }
#pragma unroll
    for (int off = 4; off; off >>= 1) {
        sg  += __shfl_down(sg,  off, 8);
        ss  += __shfl_down(ss,  off, 8);
        sgs += __shfl_down(sgs, off, 8);
        sgg += __shfl_down(sgg, off, 8);
    }
    if ((t & 7) == 0) {
        int tx = t >> 3;
        int base = (bc * NHS_ + hs) * 32 + tx;
        ws[OFF_TILE + 0 * TILE_PLANE + base] = sg;
        ws[OFF_TILE + 1 * TILE_PLANE + base] = ss;
        ws[OFF_TILE + 2 * TILE_PLANE + base] = sgs;
        ws[OFF_TILE + 3 * TILE_PLANE + base] = sgg;
    }
    if (blk == 0 && t < 132) ws[OFF_STATS + t] = 0.f;
}

__device__ __forceinline__ void bar16(float* ws, int idx) {
    __syncthreads();
    if (threadIdx.x == 0) {
        __threadfence();
        int* ctr = (int*)(ws + OFF_BAR) + idx;
        __atomic_fetch_add(ctr, 1, __ATOMIC_ACQ_REL);
        while (__hip_atomic_load(ctr, __ATOMIC_ACQUIRE, __HIP_MEMORY_SCOPE_AGENT) < MIDBLK_) {
            __builtin_amdgcn_s_sleep(1);
        }
    }
    __syncthreads();
}

__global__ __launch_bounds__(1024) void kmid(
        const float* __restrict__ w1f,
        const float* __restrict__ g1f,
        const float* __restrict__ b1f,
        const float* __restrict__ w2f,
        const float* __restrict__ g2f,
        const float* __restrict__ b2f,
        const float* __restrict__ w3f,
        float* __restrict__ ws) {
    __shared__ float zbuf[256 * 33];
    __shared__ float red[16][16];
    __shared__ float scs[32], shs[32];
    int t    = threadIdx.x;
    int w    = t >> 6;
    int lane = t & 63;
    int k    = w & 3;
    int ko8  = __builtin_amdgcn_readfirstlane(k * 8);
    int pl   = (w >> 2) * 64 + lane;
    int p    = blockIdx.x * 256 + pl;
    bool ok  = p < NP_;
    int pp   = ok ? p : 0;
    int b    = pp / NPOSPB_;
    int r    = pp % NPOSPB_;
    int oy   = r / OH_, ox = r % OH_;

    float h[6], mxv[3], myv[3];
#pragma unroll
    for (int c = 0; c < 3; c++) {
        int bc = b * 3 + c;
        int base = (bc * NHS_ + oy * 2) * 32 + ox;
        float S[4];
#pragma unroll
        for (int plane = 0; plane < 4; plane++) {
            const float* tp = ws + OFF_TILE + plane * TILE_PLANE + base;
            S[plane] = ((tp[0]  + tp[1])  + (tp[32] + tp[33]))
                     + ((tp[64] + tp[65]) + (tp[96] + tp[97]));
        }
        const float inv = 1.f / 4096.f;
        float mx = S[0] * inv, my = S[1] * inv;
        h[c]     = S[2] * inv - mx * my;
        h[3 + c] = S[3] * inv - mx * mx;
        mxv[c] = mx; myv[c] = my;
    }
    float a[8];
#pragma unroll
    for (int j = 0; j < 8; j++) {
        float y = 0.f;
#pragma unroll
        for (int i = 0; i < 6; i++) y += w1f[(ko8 + j) * 6 + i] * h[i];
        a[j] = y;
    }
    {
        float sv[8], sq[8];
#pragma unroll
        for (int j = 0; j < 8; j++) { sv[j] = ok ? a[j] : 0.f; sq[j] = sv[j] * sv[j]; }
#pragma unroll
        for (int off = 32; off; off >>= 1) {
#pragma unroll
            for (int j = 0; j < 8; j++) {
                sv[j] += __shfl_down(sv[j], off, 64);
                sq[j] += __shfl_down(sq[j], off, 64);
            }
        }
        if (lane == 0) {
#pragma unroll
            for (int j = 0; j < 8; j++) { red[w][j] = sv[j]; red[w][8 + j] = sq[j]; }
        }
    }
    __syncthreads();
    if (t < 64) {
        int o = t & 31; int kk = o >> 3; int col = ((t >= 32) ? 8 : 0) + (o & 7);
        float tot = red[kk][col] + red[kk + 4][col] + red[kk + 8][col] + red[kk + 12][col];
        atomicAdd(&ws[OFF_STATS + ((t >= 32) ? 32 : 0) + o], tot);
    }
    bar16(ws, 0);
    if (t < 32) {
        float sm = __hip_atomic_load(&ws[OFF_STATS + t],      __ATOMIC_RELAXED, __HIP_MEMORY_SCOPE_AGENT);
        float sq = __hip_atomic_load(&ws[OFF_STATS + 32 + t], __ATOMIC_RELAXED, __HIP_MEMORY_SCOPE_AGENT);
        float m = sm * (1.f / NP_);
        float v = sq * (1.f / NP_) - m * m;
        float sc = g1f[t] * rsqrtf(v + EPS_);
        scs[t] = sc; shs[t] = b1f[t] - m * sc;
    }
    __syncthreads();
#pragma unroll
    for (int j = 0; j < 8; j++) {
        float zz = fmaxf(a[j] * scs[ko8 + j] + shs[ko8 + j], 0.f);
        zbuf[pl * 33 + ko8 + j] = zz;
    }
    __syncthreads();
    float zal[32];
#pragma unroll
    for (int i = 0; i < 32; i++) zal[i] = zbuf[pl * 33 + i];
    float y2[8];
#pragma unroll
    for (int j = 0; j < 8; j++) {
        float y = 0.f;
#pragma unroll
        for (int i = 0; i < 32; i++) y += w2f[(ko8 + j) * 32 + i] * zal[i];
        y2[j] = y;
    }
    {
        float sv[8], sq[8];
#pragma unroll
        for (int j = 0; j < 8; j++) { sv[j] = ok ? y2[j] : 0.f; sq[j] = sv[j] * sv[j]; }
#pragma unroll
        for (int off = 32; off; off >>= 1) {
#pragma unroll
            for (int j = 0; j < 8; j++) {
                sv[j] += __shfl_down(sv[j], off, 64);
                sq[j] += __shfl_down(sq[j], off, 64);
            }
        }
        if (lane == 0) {
#pragma unroll
            for (int j = 0; j < 8; j++) { red[w][j] = sv[j]; red[w][8 + j] = sq[j]; }
        }
    }
    __syncthreads();
    if (t < 64) {
        int o = t & 31; int kk = o >> 3; int col = ((t >= 32) ? 8 : 0) + (o & 7);
        float tot = red[kk][col] + red[kk + 4][col] + red[kk + 8][col] + red[kk + 12][col];
        atomicAdd(&ws[OFF_STATS + 64 + ((t >= 32) ? 32 : 0) + o], tot);
    }
    bar16(ws, 1);
    if (t < 32) {
        float sm = __hip_atomic_load(&ws[OFF_STATS + 64 + t], __ATOMIC_RELAXED, __HIP_MEMORY_SCOPE_AGENT);
        float sq = __hip_atomic_load(&ws[OFF_STATS + 96 + t], __ATOMIC_RELAXED, __HIP_MEMORY_SCOPE_AGENT);
        float m = sm * (1.f / NP_);
        float v = sq * (1.f / NP_) - m * m;
        float sc = g2f[t] * rsqrtf(v + EPS_);
        scs[t] = sc; shs[t] = b2f[t] - m * sc;
    }
    __syncthreads();
#pragma unroll
    for (int j = 0; j < 8; j++) {
        float zz = fmaxf(y2[j] * scs[ko8 + j] + shs[ko8 + j], 0.f);
        zbuf[pl * 33 + ko8 + j] = zz;
    }
    __syncthreads();
    if (k == 0 && ok) {
        float z2[32];
#pragma unroll
        for (int i = 0; i < 32; i++) z2[i] = zbuf[pl * 33 + i];
#pragma unroll
        for (int c = 0; c < 3; c++) {
            float av = 0.f;
#pragma unroll
            for (int i = 0; i < 32; i++) av += w3f[c * 32 + i] * z2[i];
            ws[OFF_A  + c * NP_ + p] = av;
            ws[OFF_BV + c * NP_ + p] = myv[c] - av * mxv[c];
        }
    }
}

__global__ __launch_bounds__(256) void k5_final(
        const float* __restrict__ g,
        const float* __restrict__ ws,
        float* __restrict__ out) {
    int blk = blockIdx.x;
    int y  = blk & 1023;
    int bc = blk >> 10;
    int b = bc / 3, c = bc % 3;
    float fy = (float)y * (30.f / 1023.f);
    int y0 = (int)fy;
    float wy = fy - (float)y0;
    int y1i = min(y0 + 1, 30);
    const float* A0 = ws + OFF_A  + c * NP_ + b * NPOSPB_ + y0  * OH_;
    const float* A1 = ws + OFF_A  + c * NP_ + b * NPOSPB_ + y1i * OH_;
    const float* B0 = ws + OFF_BV + c * NP_ + b * NPOSPB_ + y0  * OH_;
    const float* B1 = ws + OFF_BV + c * NP_ + b * NPOSPB_ + y1i * OH_;
    int t = threadIdx.x;
    size_t rowoff = ((size_t)bc * H_ + (size_t)y) * W_;
    const f4* gp = (const f4*)(g + rowoff);
    f4* op = (f4*)(out + rowoff);
    f4 gv = gp[t];
    float go[4] = { gv.x, gv.y, gv.z, gv.w };
    float r[4];
#pragma unroll
    for (int j = 0; j < 4; j++) {
        int x = t * 4 + j;
        float fx = (float)x * (30.f / 1023.f);
        int x0 = (int)fx;
        float wx = fx - (float)x0;
        int x1 = min(x0 + 1, 30);
        float a  = (A0[x0] * (1.f - wx) + A0[x1] * wx) * (1.f - wy)
                 + (A1[x0] * (1.f - wx) + A1[x1] * wx) * wy;
        float bb = (B0[x0] * (1.f - wx) + B0[x1] * wx) * (1.f - wy)
                 + (B1[x0] * (1.f - wx) + B1[x1] * wx) * wy;
        r[j] = a * go[j] + bb;
    }
    f4 ov;
    ov.x = r[0]; ov.y = r[1]; ov.z = r[2]; ov.w = r[3];
    __builtin_nontemporal_store(ov, op + t);
}

extern "C" void kernel_launch(void* const* d_in, const int* in_sizes, int n_in,
                              void* d_out, int out_size, void* d_ws, size_t ws_size,
                              hipStream_t stream) {
    const float* guide = (const float*)d_in[0];
    const float* src   = (const float*)d_in[1];
    // d_in[2] = box_w (all ones) -- unused; N == 4096 everywhere (VALID padding)
    const float* w1 = (const float*)d_in[3];
    const float* g1 = (const float*)d_in[4];
    const float* b1 = (const float*)d_in[5];
    const float* w2 = (const float*)d_in[6];
    const float* g2 = (const float*)d_in[7];
    const float* b2 = (const float*)d_in[8];
    const float* w3 = (const float*)d_in[9];
    float* ws = (float*)d_ws;
    float* out = (float*)d_out;

    void* args[] = { (void*)&guide, (void*)&src,
                     (void*)&w1, (void*)&g1, (void*)&b1,
                     (void*)&w2, (void*)&g2, (void*)&b2, (void*)&w3,
                     (void*)&ws, (void*)&out };
    hipError_t e = hipLaunchCooperativeKernel((const void*)fused,
                                              dim3(NBLK_), dim3(1024), args, 0, stream);
    if (e != hipSuccess) {
        // Fallback: round-4 pipeline (proven 181.8 us)
        hipLaunchKernelGGL(k1_tilesums, dim3(B_ * C_ * NHS_), dim3(256),  0, stream, guide, src, ws);
        hipLaunchKernelGGL(kmid,        dim3(MIDBLK_),        dim3(1024), 0, stream,
                           w1, g1, b1, w2, g2, b2, w3, ws);
        hipLaunchKernelGGL(k5_final,    dim3(B_ * C_ * H_),   dim3(256),  0, stream, guide, ws, out);
    }
}

// Round 6
// 233.709 us; speedup vs baseline: 2.1918x; 2.1918x over previous
//
#include <hip/hip_runtime.h>
#include <stdint.h>

// Problem constants
#define B_      4
#define C_      3
#define H_      1024
#define W_      1024
#define OH_     31          // (1024-64)/32 + 1
#define NHS_    64          // 16-row half-strips per image
#define NP_     3844        // B * OH * OH
#define NPOSPB_ 961         // OH*OH
#define EPS_    1e-5f

#define NBLK_    192        // 192 blocks x 1024 threads; <= 256 CUs -> co-resident by construction
#define MIDBLK_  16         // blocks that run the MLP middle
#define NSHARD_  8
#define SHARD_TGT_ 24       // 192 / 8
#define LINE_    32         // ints per 128B line (pad counters to own lines)

// ---------------- ws layout (float offsets) ----------------
#define TILE_PLANE 24576    // 12 bc * 64 hs * 32 tx
#define OFF_TILE  0         // 4 planes * 24576 = 98304
#define OFF_STATS 98304     // 128 floats: s1 sum[32], s1 sq[32], s2 sum[32], s2 sq[32]
#define OFF_A     98432     // 3 * 3844
#define OFF_BV    109964    // 3 * 3844  (end 121496 floats ~= 486 KB; L3-resident)

typedef float f4 __attribute__((ext_vector_type(4)));

// ---------------- parity-versioned barrier state (device globals, zero-init) ----------------
// Launch with parity P uses set P (zeroed). The unique mid block that completes
// g_done[P] resets set P^1 and flips g_parity -> next launch uses a clean set.
// No exit barrier, no per-launch init kernel, immune to ws poisoning.
__device__ int g_shard[2][NSHARD_ * LINE_];
__device__ int g_root[2][LINE_];
__device__ int g_bn1[2][LINE_];
__device__ int g_bn2[2][LINE_];
__device__ int g_done[2][LINE_];
__device__ int g_parity;

static __device__ __forceinline__ int  aload(int* p)  { return __hip_atomic_load(p, __ATOMIC_ACQUIRE, __HIP_MEMORY_SCOPE_AGENT); }
static __device__ __forceinline__ int  aadd(int* p, int v) { return __hip_atomic_fetch_add(p, v, __ATOMIC_ACQ_REL, __HIP_MEMORY_SCOPE_AGENT); }
static __device__ __forceinline__ void astoref(float* p, float v) { __hip_atomic_store(p, v, __ATOMIC_RELAXED, __HIP_MEMORY_SCOPE_AGENT); }
static __device__ __forceinline__ void astorei(int* p, int v)     { __hip_atomic_store(p, v, __ATOMIC_RELAXED, __HIP_MEMORY_SCOPE_AGENT); }
static __device__ __forceinline__ float aloadf(float* p) { return __hip_atomic_load(p, __ATOMIC_RELAXED, __HIP_MEMORY_SCOPE_AGENT); }

// ============================================================================
// Single fused kernel, 192 blocks x 1024 threads, NON-cooperative launch.
//  phase1 (all): 4 half-strip partial-sum units per block (== proven k1 work);
//                tile partials written with AGENT-SCOPE stores (visible across
//                XCDs once vmcnt drains -> NO threadfence / L2 writeback ever).
//  bar0: sharded arrival (8 lines x 24 + 8 leader RMWs on root).
//  mid (blocks 0..15): round-4-proven 4-wave channel-split MLP body; BN
//                barriers = 16-RMW single-line (proven scale); A/b agent-stored.
//  done: mid blocks bump g_done; completer resets other parity set + flips.
//  phase5 (all): spin g_done==16, then bilinear upsample (64 rows/block).
// ============================================================================
__global__ __launch_bounds__(1024) void fused(
        const float* __restrict__ g,
        const float* __restrict__ s,
        const float* __restrict__ w1f,
        const float* __restrict__ g1f,
        const float* __restrict__ b1f,
        const float* __restrict__ w2f,
        const float* __restrict__ g2f,
        const float* __restrict__ b2f,
        const float* __restrict__ w3f,
        float* __restrict__ ws,
        float* __restrict__ out) {
    __shared__ float zbuf[256 * 33];     // [pos_local][ch] padded stride 33 (mid only)
    __shared__ float red[16][16];
    __shared__ float scs[32], shs[32];
    __shared__ int sP;
    int t  = threadIdx.x;
    int fb = blockIdx.x;
    if (t == 0) sP = __hip_atomic_load(&g_parity, __ATOMIC_RELAXED, __HIP_MEMORY_SCOPE_AGENT);

    // ---------------- phase 1: tile partial sums (4 half-strip units per block) ----------------
    {
        int sub = t >> 8;                 // 0..3 (wave-aligned)
        int st  = t & 255;
        int blk = fb * 4 + sub;           // original k1 unit id 0..767
        int bc = blk >> 6;
        int hs = blk & 63;
        const f4* gp = (const f4*)(g + ((size_t)bc * H_ + (size_t)hs * 16) * W_);
        const f4* sp = (const f4*)(s + ((size_t)bc * H_ + (size_t)hs * 16) * W_);
        float sg = 0.f, ss = 0.f, sgs = 0.f, sgg = 0.f;
#pragma unroll 4
        for (int r = 0; r < 16; r++) {
            f4 gv = gp[r * (W_ / 4) + st];
            f4 sv = __builtin_nontemporal_load(sp + r * (W_ / 4) + st);  // src read exactly once
            sg  += (gv.x + gv.y) + (gv.z + gv.w);
            ss  += (sv.x + sv.y) + (sv.z + sv.w);
            sgs += gv.x * sv.x + gv.y * sv.y + gv.z * sv.z + gv.w * sv.w;
            sgg += gv.x * gv.x + gv.y * gv.y + gv.z * gv.z + gv.w * gv.w;
        }
#pragma unroll
        for (int off = 4; off; off >>= 1) {
            sg  += __shfl_down(sg,  off, 8);
            ss  += __shfl_down(ss,  off, 8);
            sgs += __shfl_down(sgs, off, 8);
            sgg += __shfl_down(sgg, off, 8);
        }
        if ((st & 7) == 0) {
            int tx = st >> 3;
            int base = (bc * NHS_ + hs) * 32 + tx;
            // agent-scope stores: coherent once retired, no fence needed anywhere
            astoref(&ws[OFF_TILE + 0 * TILE_PLANE + base], sg);
            astoref(&ws[OFF_TILE + 1 * TILE_PLANE + base], ss);
            astoref(&ws[OFF_TILE + 2 * TILE_PLANE + base], sgs);
            astoref(&ws[OFF_TILE + 3 * TILE_PLANE + base], sgg);
        }
        if (fb == 0 && t < 128) astoref(&ws[OFF_STATS + t], 0.f);   // zero stats (ws is poisoned)
    }
    __syncthreads();                      // drains every thread's vmcnt -> stores visible
    int P = sP;

    // bar0 arrival: sharded (24 same-shard RMWs per line, 8 leader RMWs on root)
    if (t == 0) {
        int sh = fb & (NSHARD_ - 1);
        int old = aadd(&g_shard[P][sh * LINE_], 1);
        if (old == SHARD_TGT_ - 1) aadd(&g_root[P][0], 1);
    }

    if (fb < MIDBLK_) {
        // ================= mid phases (round-4-proven body) =================
        if (t == 0) { while (aload(&g_root[P][0]) < NSHARD_) __builtin_amdgcn_s_sleep(8); }
        __syncthreads();                  // all 768 tile units visible

        int w    = t >> 6;
        int lane = t & 63;
        int k    = w & 3;                                    // channel group 0..3
        int ko8  = __builtin_amdgcn_readfirstlane(k * 8);    // wave-uniform weight base (s_load)
        int pl   = (w >> 2) * 64 + lane;                     // local position 0..255
        int p    = fb * 256 + pl;
        bool ok  = p < NP_;
        int pp   = ok ? p : 0;
        int b    = pp / NPOSPB_;
        int r    = pp % NPOSPB_;
        int oy   = r / OH_, ox = r % OH_;

        // ---- phase A: window sums -> h -> conv1 (my 8 channels) ----
        float h[6], mxv[3], myv[3];
#pragma unroll
        for (int c = 0; c < 3; c++) {
            int bc = b * 3 + c;
            int base = (bc * NHS_ + oy * 2) * 32 + ox;
            float S[4];
#pragma unroll
            for (int plane = 0; plane < 4; plane++) {
                const float* tp = ws + OFF_TILE + plane * TILE_PLANE + base;
                S[plane] = ((tp[0]  + tp[1])  + (tp[32] + tp[33]))
                         + ((tp[64] + tp[65]) + (tp[96] + tp[97]));
            }
            const float inv = 1.f / 4096.f;
            float mx = S[0] * inv, my = S[1] * inv;
            h[c]     = S[2] * inv - mx * my;
            h[3 + c] = S[3] * inv - mx * mx;
            mxv[c] = mx; myv[c] = my;
        }
        float a[8];
#pragma unroll
        for (int j = 0; j < 8; j++) {
            float y = 0.f;
#pragma unroll
            for (int i = 0; i < 6; i++) y += w1f[(ko8 + j) * 6 + i] * h[i];
            a[j] = y;
        }

        // stats1: per-wave shuffle reduce -> LDS -> cross-wave -> atomicAdd (device-scope)
        {
            float sv[8], sq[8];
#pragma unroll
            for (int j = 0; j < 8; j++) { sv[j] = ok ? a[j] : 0.f; sq[j] = sv[j] * sv[j]; }
#pragma unroll
            for (int off = 32; off; off >>= 1) {
#pragma unroll
                for (int j = 0; j < 8; j++) {
                    sv[j] += __shfl_down(sv[j], off, 64);
                    sq[j] += __shfl_down(sq[j], off, 64);
                }
            }
            if (lane == 0) {
#pragma unroll
                for (int j = 0; j < 8; j++) { red[w][j] = sv[j]; red[w][8 + j] = sq[j]; }
            }
        }
        __syncthreads();
        if (t < 64) {
            int o = t & 31; int kk = o >> 3; int col = ((t >= 32) ? 8 : 0) + (o & 7);
            float tot = red[kk][col] + red[kk + 4][col] + red[kk + 8][col] + red[kk + 12][col];
            atomicAdd(&ws[OFF_STATS + ((t >= 32) ? 32 : 0) + o], tot);
        }
        __syncthreads();                  // drains adders' vmcnt
        if (t == 0) {
            aadd(&g_bn1[P][0], 1);
            while (aload(&g_bn1[P][0]) < MIDBLK_) __builtin_amdgcn_s_sleep(8);
        }
        __syncthreads();

        if (t < 32) {
            float sm = aloadf(&ws[OFF_STATS + t]);
            float sq = aloadf(&ws[OFF_STATS + 32 + t]);
            float m = sm * (1.f / NP_);
            float v = sq * (1.f / NP_) - m * m;
            float sc = g1f[t] * rsqrtf(v + EPS_);
            scs[t] = sc; shs[t] = b1f[t] - m * sc;
        }
        __syncthreads();

        // ---- phase B: BN1+ReLU -> z via LDS -> conv2 (my 8 channels) ----
#pragma unroll
        for (int j = 0; j < 8; j++) {
            float zz = fmaxf(a[j] * scs[ko8 + j] + shs[ko8 + j], 0.f);
            zbuf[pl * 33 + ko8 + j] = zz;
        }
        __syncthreads();
        float zal[32];
#pragma unroll
        for (int i = 0; i < 32; i++) zal[i] = zbuf[pl * 33 + i];   // conflict-free
        float y2[8];
#pragma unroll
        for (int j = 0; j < 8; j++) {
            float y = 0.f;
#pragma unroll
            for (int i = 0; i < 32; i++) y += w2f[(ko8 + j) * 32 + i] * zal[i];   // s_load stream
            y2[j] = y;
        }

        // stats2
        {
            float sv[8], sq[8];
#pragma unroll
            for (int j = 0; j < 8; j++) { sv[j] = ok ? y2[j] : 0.f; sq[j] = sv[j] * sv[j]; }
#pragma unroll
            for (int off = 32; off; off >>= 1) {
#pragma unroll
                for (int j = 0; j < 8; j++) {
                    sv[j] += __shfl_down(sv[j], off, 64);
                    sq[j] += __shfl_down(sq[j], off, 64);
                }
            }
            if (lane == 0) {
#pragma unroll
                for (int j = 0; j < 8; j++) { red[w][j] = sv[j]; red[w][8 + j] = sq[j]; }
            }
        }
        __syncthreads();
        if (t < 64) {
            int o = t & 31; int kk = o >> 3; int col = ((t >= 32) ? 8 : 0) + (o & 7);
            float tot = red[kk][col] + red[kk + 4][col] + red[kk + 8][col] + red[kk + 12][col];
            atomicAdd(&ws[OFF_STATS + 64 + ((t >= 32) ? 32 : 0) + o], tot);
        }
        __syncthreads();
        if (t == 0) {
            aadd(&g_bn2[P][0], 1);
            while (aload(&g_bn2[P][0]) < MIDBLK_) __builtin_amdgcn_s_sleep(8);
        }
        __syncthreads();

        if (t < 32) {
            float sm = aloadf(&ws[OFF_STATS + 64 + t]);
            float sq = aloadf(&ws[OFF_STATS + 96 + t]);
            float m = sm * (1.f / NP_);
            float v = sq * (1.f / NP_) - m * m;
            float sc = g2f[t] * rsqrtf(v + EPS_);
            scs[t] = sc; shs[t] = b2f[t] - m * sc;
        }
        __syncthreads();

        // ---- phase C: BN2+ReLU -> z2 via LDS -> conv3 -> A, b (agent-stored) ----
#pragma unroll
        for (int j = 0; j < 8; j++) {
            float zz = fmaxf(y2[j] * scs[ko8 + j] + shs[ko8 + j], 0.f);
            zbuf[pl * 33 + ko8 + j] = zz;     // safe: conv2-era reads done before bn2 barrier
        }
        __syncthreads();
        if (k == 0 && ok) {
            float z2[32];
#pragma unroll
            for (int i = 0; i < 32; i++) z2[i] = zbuf[pl * 33 + i];
#pragma unroll
            for (int c = 0; c < 3; c++) {
                float av = 0.f;
#pragma unroll
                for (int i = 0; i < 32; i++) av += w3f[c * 32 + i] * z2[i];
                astoref(&ws[OFF_A  + c * NP_ + p], av);
                astoref(&ws[OFF_BV + c * NP_ + p], myv[c] - av * mxv[c]);
            }
        }
        __syncthreads();                  // drain A/b agent stores
        if (t == 0) {
            int old = aadd(&g_done[P][0], 1);
            if (old == MIDBLK_ - 1) {
                // completer: reset the OTHER parity set (unused this launch), flip parity
                int Q = P ^ 1;
#pragma unroll
                for (int i = 0; i < NSHARD_; i++) astorei(&g_shard[Q][i * LINE_], 0);
                astorei(&g_root[Q][0], 0);
                astorei(&g_bn1[Q][0], 0);
                astorei(&g_bn2[Q][0], 0);
                astorei(&g_done[Q][0], 0);
                __hip_atomic_store(&g_parity, Q, __ATOMIC_RELEASE, __HIP_MEMORY_SCOPE_AGENT);
            }
        }
    }

    // ---------------- all blocks: wait for A/b, then phase 5 ----------------
    if (t == 0) { while (aload(&g_done[P][0]) < MIDBLK_) __builtin_amdgcn_s_sleep(16); }
    __syncthreads();

    // phase 5: bilinear upsample + out = A*g + b (64 rows/block; bc uniform since 64 | 1024)
    {
        int sub = t >> 8;
        int st  = t & 255;
        int row0 = fb * 64 + sub * 16;
        int bc = row0 >> 10;
        int b5 = bc / 3, c5 = bc % 3;
        const float* Abase = ws + OFF_A  + c5 * NP_ + b5 * NPOSPB_;
        const float* Bbase = ws + OFF_BV + c5 * NP_ + b5 * NPOSPB_;
        int x0_[4], x1_[4]; float wx_[4];
#pragma unroll
        for (int j = 0; j < 4; j++) {
            int x = st * 4 + j;
            float fx = (float)x * (30.f / 1023.f);
            int x0 = (int)fx;
            wx_[j] = fx - (float)x0;
            x0_[j] = x0;
            x1_[j] = min(x0 + 1, 30);
        }
        for (int rr = 0; rr < 16; rr++) {
            int y = (row0 & 1023) + rr;
            float fy = (float)y * (30.f / 1023.f);
            int y0 = (int)fy;
            float wy = fy - (float)y0;
            int y1i = min(y0 + 1, 30);
            const float* A0 = Abase + y0  * OH_;
            const float* A1 = Abase + y1i * OH_;
            const float* B0 = Bbase + y0  * OH_;
            const float* B1 = Bbase + y1i * OH_;
            size_t rowoff = ((size_t)bc * H_ + (size_t)y) * W_;
            f4 gv = ((const f4*)(g + rowoff))[st];
            float go[4] = { gv.x, gv.y, gv.z, gv.w };
            float r[4];
#pragma unroll
            for (int j = 0; j < 4; j++) {
                int x0 = x0_[j], x1 = x1_[j];
                float wx = wx_[j];
                float av = (A0[x0] * (1.f - wx) + A0[x1] * wx) * (1.f - wy)
                         + (A1[x0] * (1.f - wx) + A1[x1] * wx) * wy;
                float bb = (B0[x0] * (1.f - wx) + B0[x1] * wx) * (1.f - wy)
                         + (B1[x0] * (1.f - wx) + B1[x1] * wx) * wy;
                r[j] = av * go[j] + bb;
            }
            f4 ov; ov.x = r[0]; ov.y = r[1]; ov.z = r[2]; ov.w = r[3];
            __builtin_nontemporal_store(ov, (f4*)(out + rowoff) + st);   // out never re-read
        }
    }
}

extern "C" void kernel_launch(void* const* d_in, const int* in_sizes, int n_in,
                              void* d_out, int out_size, void* d_ws, size_t ws_size,
                              hipStream_t stream) {
    const float* guide = (const float*)d_in[0];
    const float* src   = (const float*)d_in[1];
    // d_in[2] = box_w (all ones) -- unused; N == 4096 everywhere (VALID padding)
    const float* w1 = (const float*)d_in[3];
    const float* g1 = (const float*)d_in[4];
    const float* b1 = (const float*)d_in[5];
    const float* w2 = (const float*)d_in[6];
    const float* g2 = (const float*)d_in[7];
    const float* b2 = (const float*)d_in[8];
    const float* w3 = (const float*)d_in[9];
    float* ws = (float*)d_ws;
    float* out = (float*)d_out;

    // Plain (non-cooperative) launch: 192 blocks <= 256 CUs, all co-resident by
    // construction (1024 thr, 35 KB LDS, <=128 VGPR) -> spin barriers are safe.
    hipLaunchKernelGGL(fused, dim3(NBLK_), dim3(1024), 0, stream,
                       guide, src, w1, g1, b1, w2, g2, b2, w3, ws, out);
}

// Round 7
// 191.577 us; speedup vs baseline: 2.6738x; 1.2199x over previous
//
#include <hip/hip_runtime.h>
#include <stdint.h>

// Problem constants
#define B_      4
#define C_      3
#define H_      1024
#define W_      1024
#define OH_     31          // (1024-64)/32 + 1
#define NHS_    64          // 16-row half-strips per image
#define NP_     3844        // B * OH * OH
#define NPOSPB_ 961         // OH*OH
#define EPS_    1e-5f

#define NBLK_    256        // 256 blocks x 768 threads; 1 block/CU, all co-resident
#define NTHR_    768
#define MIDBLK_  21         // blocks that run the MLP middle (21*192 = 4032 >= 3844)
#define NSHARD_  8
#define SHARD_TGT_ 32       // 256 / 8
#define LINE_    32         // ints per 128B line (pad counters to own lines)

// ---------------- ws layout (float offsets) ----------------
#define TILE_PLANE 24576    // 12 bc * 64 hs * 32 tx
#define OFF_TILE  0         // 4 planes * 24576 = 98304
#define OFF_STATS 98304     // 128 floats: s1 sum[32], s1 sq[32], s2 sum[32], s2 sq[32]
#define OFF_A     98432     // 3 * 3844
#define OFF_BV    109964    // 3 * 3844  (end 121496 floats ~= 486 KB; L3-resident)

typedef float f4 __attribute__((ext_vector_type(4)));

// ---------------- parity-versioned barrier state (device globals, zero-init) ----------------
// Launch with parity P uses set P (zeroed). The unique mid block that completes
// g_done[P] resets set P^1 and flips g_parity -> next launch sees a clean set.
// No exit barrier, no init kernel, immune to ws poisoning.
__device__ int g_shard[2][NSHARD_ * LINE_];
__device__ int g_root[2][LINE_];
__device__ int g_bn1[2][LINE_];
__device__ int g_bn2[2][LINE_];
__device__ int g_done[2][LINE_];
__device__ int g_parity;

// Polls are RELAXED agent loads (read-through to the coherent point, NO cache
// maintenance). Round-6 lesson: acquire-per-poll emits buffer_inv (L2
// invalidate) every iteration -> 176 waiters x ~2/us = continuous L2-inv storm
// on all XCDs during the mid phase (its 122-vs-65us gap). After the predicate
// passes, ONE acquire load performs the single invalidate + ordering needed to
// read agent-stored data with plain (cacheable) loads.
static __device__ __forceinline__ int  rload(int* p) { return __hip_atomic_load(p, __ATOMIC_RELAXED, __HIP_MEMORY_SCOPE_AGENT); }
static __device__ __forceinline__ int  aacq(int* p)  { return __hip_atomic_load(p, __ATOMIC_ACQUIRE, __HIP_MEMORY_SCOPE_AGENT); }
static __device__ __forceinline__ int  aadd(int* p, int v) { return __hip_atomic_fetch_add(p, v, __ATOMIC_ACQ_REL, __HIP_MEMORY_SCOPE_AGENT); }
static __device__ __forceinline__ void astoref(float* p, float v) { __hip_atomic_store(p, v, __ATOMIC_RELAXED, __HIP_MEMORY_SCOPE_AGENT); }
static __device__ __forceinline__ void astorei(int* p, int v)     { __hip_atomic_store(p, v, __ATOMIC_RELAXED, __HIP_MEMORY_SCOPE_AGENT); }
static __device__ __forceinline__ float aloadf(float* p) { return __hip_atomic_load(p, __ATOMIC_RELAXED, __HIP_MEMORY_SCOPE_AGENT); }

#define SPIN(ctr, target, slp) do { \
    if (t == 0) { \
        while (rload(ctr) < (target)) __builtin_amdgcn_s_sleep(slp); \
        (void)aacq(ctr);   /* single invalidate + acquire ordering */ \
    } \
    __syncthreads(); \
} while (0)

// ============================================================================
// Single fused kernel, 256 blocks x 768 threads, plain launch (co-resident by
// construction: 12 waves, ~27 KB LDS, low VGPR -> 1 block/CU).
//  phase1 (all): 3 half-strip units/block (units 768 = 256*3, all CUs busy);
//                tile partials agent-stored (write-through, no fences ever).
//  bar0: sharded arrival (8 lines x 32 + 8 leader RMWs on root).
//  mid (blocks 0..20): 12-wave channel-split MLP; 192 positions/block;
//                BN barriers = 21-RMW single line; A/b agent-stored.
//  phase5 (all): spin g_done==21 (relaxed), upsample 48 rows/block.
//                Phase-5 rows of block fb == phase-1 rows of block fb
//                (48fb+16sub both) -> g re-read hits local L2/L3.
// ============================================================================
__global__ __launch_bounds__(NTHR_) void fused(
        const float* __restrict__ g,
        const float* __restrict__ s,
        const float* __restrict__ w1f,
        const float* __restrict__ g1f,
        const float* __restrict__ b1f,
        const float* __restrict__ w2f,
        const float* __restrict__ g2f,
        const float* __restrict__ b2f,
        const float* __restrict__ w3f,
        float* __restrict__ ws,
        float* __restrict__ out) {
    __shared__ float zbuf[192 * 33];     // [pos_local][ch] padded stride 33 (mid only)
    __shared__ float red[12][16];        // per-wave stats partials
    __shared__ float scs[32], shs[32];
    __shared__ int sP;
    int t  = threadIdx.x;
    int fb = blockIdx.x;
    if (t == 0) sP = __hip_atomic_load(&g_parity, __ATOMIC_RELAXED, __HIP_MEMORY_SCOPE_AGENT);

    // ---------------- phase 1: tile partial sums (3 half-strip units per block) ----------------
    {
        int sub = t >> 8;                 // 0..2 (wave-aligned: 256 = 4 waves)
        int st  = t & 255;
        int unit = fb * 3 + sub;          // 0..767
        int bc = unit >> 6;
        int hs = unit & 63;
        const f4* gp = (const f4*)(g + ((size_t)bc * H_ + (size_t)hs * 16) * W_);
        const f4* sp = (const f4*)(s + ((size_t)bc * H_ + (size_t)hs * 16) * W_);
        float sg = 0.f, ss = 0.f, sgs = 0.f, sgg = 0.f;
#pragma unroll 4
        for (int r = 0; r < 16; r++) {
            f4 gv = gp[r * (W_ / 4) + st];
            f4 sv = __builtin_nontemporal_load(sp + r * (W_ / 4) + st);  // src read exactly once
            sg  += (gv.x + gv.y) + (gv.z + gv.w);
            ss  += (sv.x + sv.y) + (sv.z + sv.w);
            sgs += gv.x * sv.x + gv.y * sv.y + gv.z * sv.z + gv.w * sv.w;
            sgg += gv.x * gv.x + gv.y * gv.y + gv.z * gv.z + gv.w * gv.w;
        }
#pragma unroll
        for (int off = 4; off; off >>= 1) {
            sg  += __shfl_down(sg,  off, 8);
            ss  += __shfl_down(ss,  off, 8);
            sgs += __shfl_down(sgs, off, 8);
            sgg += __shfl_down(sgg, off, 8);
        }
        if ((st & 7) == 0) {
            int tx = st >> 3;
            int base = (bc * NHS_ + hs) * 32 + tx;
            // agent-scope stores: land at the coherent point, no fence needed
            astoref(&ws[OFF_TILE + 0 * TILE_PLANE + base], sg);
            astoref(&ws[OFF_TILE + 1 * TILE_PLANE + base], ss);
            astoref(&ws[OFF_TILE + 2 * TILE_PLANE + base], sgs);
            astoref(&ws[OFF_TILE + 3 * TILE_PLANE + base], sgg);
        }
        if (fb == 0 && t < 128) astoref(&ws[OFF_STATS + t], 0.f);   // zero stats (ws is poisoned)
    }
    __syncthreads();                      // drains every thread's vmcnt -> stores visible
    int P = sP;

    // bar0 arrival: sharded (32 same-shard RMWs per line, 8 leader RMWs on root)
    if (t == 0) {
        int sh = fb & (NSHARD_ - 1);
        int old = aadd(&g_shard[P][sh * LINE_], 1);
        if (old == SHARD_TGT_ - 1) aadd(&g_root[P][0], 1);
    }

    if (fb < MIDBLK_) {
        // ================= mid phases (proven channel-split body, 12 waves) =================
        SPIN(&g_root[P][0], NSHARD_, 2);  // all 768 tile units visible (+1 invalidate)

        int w    = t >> 6;                                   // wave 0..11
        int lane = t & 63;
        int k    = w & 3;                                    // channel group 0..3
        int ko8  = __builtin_amdgcn_readfirstlane(k * 8);    // wave-uniform weight base (s_load)
        int pl   = (w >> 2) * 64 + lane;                     // local position 0..191
        int p    = fb * 192 + pl;
        bool ok  = p < NP_;
        int pp   = ok ? p : 0;
        int b    = pp / NPOSPB_;
        int r    = pp % NPOSPB_;
        int oy   = r / OH_, ox = r % OH_;

        // ---- phase A: window sums -> h -> conv1 (my 8 channels) ----
        float h[6], mxv[3], myv[3];
#pragma unroll
        for (int c = 0; c < 3; c++) {
            int bc = b * 3 + c;
            int base = (bc * NHS_ + oy * 2) * 32 + ox;
            float S[4];
#pragma unroll
            for (int plane = 0; plane < 4; plane++) {
                const float* tp = ws + OFF_TILE + plane * TILE_PLANE + base;
                S[plane] = ((tp[0]  + tp[1])  + (tp[32] + tp[33]))
                         + ((tp[64] + tp[65]) + (tp[96] + tp[97]));
            }
            const float inv = 1.f / 4096.f;
            float mx = S[0] * inv, my = S[1] * inv;
            h[c]     = S[2] * inv - mx * my;
            h[3 + c] = S[3] * inv - mx * mx;
            mxv[c] = mx; myv[c] = my;
        }
        float a[8];
#pragma unroll
        for (int j = 0; j < 8; j++) {
            float y = 0.f;
#pragma unroll
            for (int i = 0; i < 6; i++) y += w1f[(ko8 + j) * 6 + i] * h[i];
            a[j] = y;
        }

        // stats1: per-wave shuffle reduce -> LDS -> cross-wave -> atomicAdd
        {
            float sv[8], sq[8];
#pragma unroll
            for (int j = 0; j < 8; j++) { sv[j] = ok ? a[j] : 0.f; sq[j] = sv[j] * sv[j]; }
#pragma unroll
            for (int off = 32; off; off >>= 1) {
#pragma unroll
                for (int j = 0; j < 8; j++) {
                    sv[j] += __shfl_down(sv[j], off, 64);
                    sq[j] += __shfl_down(sq[j], off, 64);
                }
            }
            if (lane == 0) {
#pragma unroll
                for (int j = 0; j < 8; j++) { red[w][j] = sv[j]; red[w][8 + j] = sq[j]; }
            }
        }
        __syncthreads();
        if (t < 64) {
            int o = t & 31; int kk = o >> 3; int col = ((t >= 32) ? 8 : 0) + (o & 7);
            float tot = red[kk][col] + red[kk + 4][col] + red[kk + 8][col];   // pw = 0,1,2
            atomicAdd(&ws[OFF_STATS + ((t >= 32) ? 32 : 0) + o], tot);
        }
        __syncthreads();                  // drains adders' vmcnt
        if (t == 0) aadd(&g_bn1[P][0], 1);
        SPIN(&g_bn1[P][0], MIDBLK_, 2);

        if (t < 32) {
            float sm = aloadf(&ws[OFF_STATS + t]);        // read-through: atomics' home
            float sq = aloadf(&ws[OFF_STATS + 32 + t]);
            float m = sm * (1.f / NP_);
            float v = sq * (1.f / NP_) - m * m;
            float sc = g1f[t] * rsqrtf(v + EPS_);
            scs[t] = sc; shs[t] = b1f[t] - m * sc;
        }
        __syncthreads();

        // ---- phase B: BN1+ReLU -> z via LDS -> conv2 (my 8 channels) ----
#pragma unroll
        for (int j = 0; j < 8; j++) {
            float zz = fmaxf(a[j] * scs[ko8 + j] + shs[ko8 + j], 0.f);
            zbuf[pl * 33 + ko8 + j] = zz;
        }
        __syncthreads();
        float zal[32];
#pragma unroll
        for (int i = 0; i < 32; i++) zal[i] = zbuf[pl * 33 + i];   // conflict-free
        float y2[8];
#pragma unroll
        for (int j = 0; j < 8; j++) {
            float y = 0.f;
#pragma unroll
            for (int i = 0; i < 32; i++) y += w2f[(ko8 + j) * 32 + i] * zal[i];   // s_load stream
            y2[j] = y;
        }

        // stats2
        {
            float sv[8], sq[8];
#pragma unroll
            for (int j = 0; j < 8; j++) { sv[j] = ok ? y2[j] : 0.f; sq[j] = sv[j] * sv[j]; }
#pragma unroll
            for (int off = 32; off; off >>= 1) {
#pragma unroll
                for (int j = 0; j < 8; j++) {
                    sv[j] += __shfl_down(sv[j], off, 64);
                    sq[j] += __shfl_down(sq[j], off, 64);
                }
            }
            if (lane == 0) {
#pragma unroll
                for (int j = 0; j < 8; j++) { red[w][j] = sv[j]; red[w][8 + j] = sq[j]; }
            }
        }
        __syncthreads();
        if (t < 64) {
            int o = t & 31; int kk = o >> 3; int col = ((t >= 32) ? 8 : 0) + (o & 7);
            float tot = red[kk][col] + red[kk + 4][col] + red[kk + 8][col];
            atomicAdd(&ws[OFF_STATS + 64 + ((t >= 32) ? 32 : 0) + o], tot);
        }
        __syncthreads();
        if (t == 0) aadd(&g_bn2[P][0], 1);
        SPIN(&g_bn2[P][0], MIDBLK_, 2);

        if (t < 32) {
            float sm = aloadf(&ws[OFF_STATS + 64 + t]);
            float sq = aloadf(&ws[OFF_STATS + 96 + t]);
            float m = sm * (1.f / NP_);
            float v = sq * (1.f / NP_) - m * m;
            float sc = g2f[t] * rsqrtf(v + EPS_);
            scs[t] = sc; shs[t] = b2f[t] - m * sc;
        }
        __syncthreads();

        // ---- phase C: BN2+ReLU -> z2 via LDS -> conv3 -> A, b (agent-stored) ----
#pragma unroll
        for (int j = 0; j < 8; j++) {
            float zz = fmaxf(y2[j] * scs[ko8 + j] + shs[ko8 + j], 0.f);
            zbuf[pl * 33 + ko8 + j] = zz;     // safe: conv2-era reads done before bn2 barrier
        }
        __syncthreads();
        if (k == 0 && ok) {                   // waves 0,4,8 -> pl 0..191 covered
            float z2[32];
#pragma unroll
            for (int i = 0; i < 32; i++) z2[i] = zbuf[pl * 33 + i];
#pragma unroll
            for (int c = 0; c < 3; c++) {
                float av = 0.f;
#pragma unroll
                for (int i = 0; i < 32; i++) av += w3f[c * 32 + i] * z2[i];
                astoref(&ws[OFF_A  + c * NP_ + p], av);
                astoref(&ws[OFF_BV + c * NP_ + p], myv[c] - av * mxv[c]);
            }
        }
        __syncthreads();                  // drain A/b agent stores
        if (t == 0) {
            int old = aadd(&g_done[P][0], 1);
            if (old == MIDBLK_ - 1) {
                // completer: reset the OTHER parity set (unused this launch), flip parity
                int Q = P ^ 1;
#pragma unroll
                for (int i = 0; i < NSHARD_; i++) astorei(&g_shard[Q][i * LINE_], 0);
                astorei(&g_root[Q][0], 0);
                astorei(&g_bn1[Q][0], 0);
                astorei(&g_bn2[Q][0], 0);
                astorei(&g_done[Q][0], 0);
                __hip_atomic_store(&g_parity, Q, __ATOMIC_RELEASE, __HIP_MEMORY_SCOPE_AGENT);
            }
        }
    }

    // ---------------- all blocks: wait for A/b (relaxed poll), then phase 5 ----------------
    SPIN(&g_done[P][0], MIDBLK_, 32);

    // phase 5: bilinear upsample + out = A*g + b (48 rows/block = 3 sub x 16)
    {
        int sub = t >> 8;                 // 0..2
        int st  = t & 255;
        int row0 = fb * 48 + sub * 16;    // == phase-1 rows of this (fb,sub): L2 reuse of g
        int bc = row0 >> 10;              // 16-row chunk never crosses bc (16 | 1024)
        int b5 = bc / 3, c5 = bc % 3;
        const float* Abase = ws + OFF_A  + c5 * NP_ + b5 * NPOSPB_;
        const float* Bbase = ws + OFF_BV + c5 * NP_ + b5 * NPOSPB_;
        int x0_[4], x1_[4]; float wx_[4];
#pragma unroll
        for (int j = 0; j < 4; j++) {
            int x = st * 4 + j;
            float fx = (float)x * (30.f / 1023.f);
            int x0 = (int)fx;
            wx_[j] = fx - (float)x0;
            x0_[j] = x0;
            x1_[j] = min(x0 + 1, 30);
        }
        for (int rr = 0; rr < 16; rr++) {
            int y = (row0 & 1023) + rr;
            float fy = (float)y * (30.f / 1023.f);
            int y0 = (int)fy;
            float wy = fy - (float)y0;
            int y1i = min(y0 + 1, 30);
            const float* A0 = Abase + y0  * OH_;
            const float* A1 = Abase + y1i * OH_;
            const float* B0 = Bbase + y0  * OH_;
            const float* B1 = Bbase + y1i * OH_;
            size_t rowoff = ((size_t)bc * H_ + (size_t)y) * W_;
            f4 gv = ((const f4*)(g + rowoff))[st];
            float go[4] = { gv.x, gv.y, gv.z, gv.w };
            float r[4];
#pragma unroll
            for (int j = 0; j < 4; j++) {
                int x0 = x0_[j], x1 = x1_[j];
                float wx = wx_[j];
                float av = (A0[x0] * (1.f - wx) + A0[x1] * wx) * (1.f - wy)
                         + (A1[x0] * (1.f - wx) + A1[x1] * wx) * wy;
                float bb = (B0[x0] * (1.f - wx) + B0[x1] * wx) * (1.f - wy)
                         + (B1[x0] * (1.f - wx) + B1[x1] * wx) * wy;
                r[j] = av * go[j] + bb;
            }
            f4 ov; ov.x = r[0]; ov.y = r[1]; ov.z = r[2]; ov.w = r[3];
            __builtin_nontemporal_store(ov, (f4*)(out + rowoff) + st);   // out never re-read
        }
    }
}

extern "C" void kernel_launch(void* const* d_in, const int* in_sizes, int n_in,
                              void* d_out, int out_size, void* d_ws, size_t ws_size,
                              hipStream_t stream) {
    const float* guide = (const float*)d_in[0];
    const float* src   = (const float*)d_in[1];
    // d_in[2] = box_w (all ones) -- unused; N == 4096 everywhere (VALID padding)
    const float* w1 = (const float*)d_in[3];
    const float* g1 = (const float*)d_in[4];
    const float* b1 = (const float*)d_in[5];
    const float* w2 = (const float*)d_in[6];
    const float* g2 = (const float*)d_in[7];
    const float* b2 = (const float*)d_in[8];
    const float* w3 = (const float*)d_in[9];
    float* ws = (float*)d_ws;
    float* out = (float*)d_out;

    // Plain (non-cooperative) launch: 256 blocks x 768 threads = 1 block/CU,
    // all co-resident by construction -> spin barriers are safe.
    hipLaunchKernelGGL(fused, dim3(NBLK_), dim3(NTHR_), 0, stream,
                       guide, src, w1, g1, b1, w2, g2, b2, w3, ws, out);
}